// Round 8
// baseline (675.392 us; speedup 1.0000x reference)
//
#include <hip/hip_runtime.h>
#include <hip/hip_bf16.h>

#define NN 8192
#define KDIM 256
#define DDIM 128

typedef __attribute__((ext_vector_type(8))) short short8;
typedef __attribute__((ext_vector_type(4))) float floatx4;
typedef __attribute__((ext_vector_type(4))) int intx4;

__device__ __forceinline__ unsigned short f2bf(float x) {
    unsigned int u = __float_as_uint(x);
    return (unsigned short)((u + 0x8000u) >> 16);
}

__global__ void k_trip(float* out, float v) {
    if (threadIdx.x == 0 && blockIdx.x == 0) out[0] = v;
}

// ---------------- kA: swizzle W (256x128 fp32 row-major) into bf16 B-fragment layout
__global__ void kA_swizzleW(const float* __restrict__ W, unsigned short* __restrict__ WB) {
    int gid = blockIdx.x * blockDim.x + threadIdx.x;   // 0..4095
    int kt = gid >> 9, nt = (gid >> 6) & 7, lane = gid & 63;
    int quad = lane >> 4, c = lane & 15;
    short8 pack;
#pragma unroll
    for (int t = 0; t < 8; ++t)
        pack[t] = (short)f2bf(W[(kt * 32 + quad * 8 + t) * DDIM + nt * 16 + c]);
    *(short8*)(WB + ((size_t)(kt * 8 + nt) * 64 + lane) * 8) = pack;
}

// ---------------- kB: Wh = X @ W (bf16 MFMA); emit f, g, and WhB fragments.
__global__ __launch_bounds__(256) void kB_wh(
        const float* __restrict__ X,
        const unsigned short* __restrict__ WB,
        const float* __restrict__ a,
        unsigned short* __restrict__ WhB,
        float* __restrict__ f, float* __restrict__ g) {
    __shared__ unsigned short tile[64 * 128];
    int tid = threadIdx.x;
    int wave = tid >> 6, lane = tid & 63;
    int quad = lane >> 4, c = lane & 15;
    int rowbase = blockIdx.x * 64 + wave * 16;

    floatx4 acc[8];
#pragma unroll
    for (int nt = 0; nt < 8; ++nt) acc[nt] = (floatx4)(0.0f);

    const short8* WB8 = (const short8*)WB;
#pragma unroll
    for (int ks = 0; ks < 8; ++ks) {
        const float* xp = X + (size_t)(rowbase + c) * KDIM + ks * 32 + quad * 8;
        floatx4 x0 = *(const floatx4*)xp;
        floatx4 x1 = *(const floatx4*)(xp + 4);
        short8 afrag;
#pragma unroll
        for (int t = 0; t < 4; ++t) { afrag[t] = (short)f2bf(x0[t]); afrag[4 + t] = (short)f2bf(x1[t]); }
#pragma unroll
        for (int nt = 0; nt < 8; ++nt) {
            short8 b = WB8[(ks * 8 + nt) * 64 + lane];
            acc[nt] = __builtin_amdgcn_mfma_f32_16x16x32_bf16(afrag, b, acc[nt], 0, 0, 0);
        }
    }

    float fp[4] = {0.f, 0.f, 0.f, 0.f}, gp[4] = {0.f, 0.f, 0.f, 0.f};
#pragma unroll
    for (int nt = 0; nt < 8; ++nt) {
        float a1 = a[nt * 16 + c];
        float a2 = a[DDIM + nt * 16 + c];
#pragma unroll
        for (int r = 0; r < 4; ++r) {
            fp[r] += acc[nt][r] * a1;
            gp[r] += acc[nt][r] * a2;
        }
    }
#pragma unroll
    for (int m = 1; m < 16; m <<= 1) {
#pragma unroll
        for (int r = 0; r < 4; ++r) {
            fp[r] += __shfl_xor(fp[r], m);
            gp[r] += __shfl_xor(gp[r], m);
        }
    }
    if (c == 0) {
#pragma unroll
        for (int r = 0; r < 4; ++r) {
            f[rowbase + quad * 4 + r] = fp[r];
            g[rowbase + quad * 4 + r] = gp[r];
        }
    }

#pragma unroll
    for (int nt = 0; nt < 8; ++nt)
#pragma unroll
        for (int r = 0; r < 4; ++r)
            tile[(wave * 16 + quad * 4 + r) * 128 + nt * 16 + c] = f2bf(acc[nt][r]);
    __syncthreads();

    int kt2 = wave >> 1;
#pragma unroll
    for (int ntj = 0; ntj < 4; ++ntj) {
        int nt = (wave & 1) * 4 + ntj;
        short8 pack;
#pragma unroll
        for (int t = 0; t < 8; ++t)
            pack[t] = (short)tile[(kt2 * 32 + quad * 8 + t) * 128 + nt * 16 + c];
        *(short8*)(WhB + ((size_t)((blockIdx.x * 2 + kt2) * 8 + nt) * 64 + lane) * 8) = pack;
    }
}

// ---------------- kC4: masked-softmax attention, COLUMN-SPLIT 4-way.
// R6: 2-way split (4 blocks/CU) cut kC ~169 -> ~118 us; still latency-bound &
// grid-capped. 4-way: 2048 blocks = 8 blocks/CU (32 waves/CU, the HW cap).
// LDS shrunk to 19.5 KB (g-slice 8KB overlays merge buffers) so LDS caps at 8.
__global__ __launch_bounds__(256, 8) void kC_attn4(
        const int* __restrict__ adj,
        const unsigned short* __restrict__ WhB,
        const float* __restrict__ f, const float* __restrict__ g,
        float* __restrict__ pacc, float* __restrict__ pl) {
    __shared__ float smem[4880];    // 19.5 KB: [0,2048) g-slice, then merge overlay
    int tid = threadIdx.x;
    int wave = tid >> 6, lane = tid & 63;
    int quad = lane >> 4, c = lane & 15;
    int bq   = blockIdx.x >> 9;          // column quarter 0..3
    int brow = blockIdx.x & 511;         // 16-row group
    int rowbase = brow * 16;

    // stage this quarter's g-slice: 2048 floats
    {
        const floatx4* g4 = (const floatx4*)g;
        for (int i = tid; i < 512; i += 256)
            ((floatx4*)smem)[i] = g4[bq * 512 + i];
    }
    __syncthreads();

    float f0 = f[rowbase + c];

    floatx4 acc[8];
#pragma unroll
    for (int nt = 0; nt < 8; ++nt) acc[nt] = (floatx4)(0.0f);
    float l0 = 0.0f;

    const intx4* arow = (const intx4*)(adj + (size_t)(rowbase + c) * NN);
    const short8* WhB8 = (const short8*)WhB;
    int jbase = bq * 64;                 // J32 range [jbase, jbase+64)

    // adjacency prefetch it=0,1
    intx4 A0a = arow[(jbase + 0 * 4 + wave) * 8 + quad * 2];
    intx4 A0b = arow[(jbase + 0 * 4 + wave) * 8 + quad * 2 + 1];
    intx4 A1a = arow[(jbase + 1 * 4 + wave) * 8 + quad * 2];
    intx4 A1b = arow[(jbase + 1 * 4 + wave) * 8 + quad * 2 + 1];

    // WhB fragment prefetch for it=0
    short8 bfrA[8], bfrB[8];
#pragma unroll
    for (int nt = 0; nt < 8; ++nt)
        bfrA[nt] = WhB8[((size_t)(jbase + wave) * 8 + nt) * 64 + lane];

#define KC_STEP(ITC, BCUR, BNEXT) do {                                          \
        int j4n_ = jbase + (((ITC) + 2) & 15) * 4 + wave;                       \
        intx4 A2a_ = arow[j4n_ * 8 + quad * 2];                                 \
        intx4 A2b_ = arow[j4n_ * 8 + quad * 2 + 1];                             \
        int J32n_ = jbase + (((ITC) + 1) & 15) * 4 + wave;                      \
        _Pragma("unroll")                                                       \
        for (int nt = 0; nt < 8; ++nt)                                          \
            BNEXT[nt] = WhB8[((size_t)J32n_ * 8 + nt) * 64 + lane];             \
        int gb_ = ((ITC) * 4 + wave) * 32 + quad * 8;                           \
        floatx4 g0_ = *(const floatx4*)&smem[gb_];                              \
        floatx4 g1_ = *(const floatx4*)&smem[gb_ + 4];                          \
        short8 afr_;                                                            \
        _Pragma("unroll")                                                       \
        for (int u = 0; u < 4; ++u) {                                           \
            float x_, E_;                                                       \
            x_ = f0 + g0_[u]; x_ = fmaxf(x_, 0.2f * x_);                        \
            E_ = (A0a[u] > 0) ? __expf(x_) : 0.0f; l0 += E_;                    \
            afr_[u] = (short)f2bf(E_);                                          \
            x_ = f0 + g1_[u]; x_ = fmaxf(x_, 0.2f * x_);                        \
            E_ = (A0b[u] > 0) ? __expf(x_) : 0.0f; l0 += E_;                    \
            afr_[4 + u] = (short)f2bf(E_);                                      \
        }                                                                       \
        _Pragma("unroll")                                                       \
        for (int nt = 0; nt < 8; ++nt)                                          \
            acc[nt] = __builtin_amdgcn_mfma_f32_16x16x32_bf16(afr_, BCUR[nt],   \
                                                              acc[nt], 0, 0, 0);\
        A0a = A1a; A0b = A1b; A1a = A2a_; A1b = A2b_;                           \
    } while (0)

    for (int it = 0; it < 16; it += 2) {
        KC_STEP(it, bfrA, bfrB);
        KC_STEP(it + 1, bfrB, bfrA);
    }
#undef KC_STEP

    // ---- l partial ----
    __syncthreads();                      // g reads done; smem reusable
    smem[4608 + wave * 64 + lane] = l0;
    __syncthreads();
    if (tid < 16) {
        float s = 0.0f;
#pragma unroll
        for (int w = 0; w < 4; ++w)
#pragma unroll
            for (int q = 0; q < 4; ++q)
                s += smem[4608 + w * 64 + q * 16 + tid];
        pl[bq * NN + rowbase + tid] = s;
    }

    // ---- acc merge across 4 waves (stride-36 padded buffers at smem[0..4607]) ----
    if (wave >= 2) {
        float* b = &smem[(wave - 2) * 2304 + lane * 36];
#pragma unroll
        for (int nt = 0; nt < 8; ++nt) *(floatx4*)&b[nt * 4] = acc[nt];
    }
    __syncthreads();
    if (wave < 2) {
        float* b = &smem[wave * 2304 + lane * 36];
#pragma unroll
        for (int nt = 0; nt < 8; ++nt) acc[nt] += *(const floatx4*)&b[nt * 4];
    }
    __syncthreads();
    if (wave == 1) {
        float* b = &smem[lane * 36];
#pragma unroll
        for (int nt = 0; nt < 8; ++nt) *(floatx4*)&b[nt * 4] = acc[nt];
    }
    __syncthreads();

    // ---- write partial acc (wave 0), unnormalized ----
    if (wave == 0) {
        float* b = &smem[lane * 36];
#pragma unroll
        for (int nt = 0; nt < 8; ++nt) acc[nt] += *(const floatx4*)&b[nt * 4];
        float* pb = pacc + (size_t)bq * NN * DDIM;
#pragma unroll
        for (int nt = 0; nt < 8; ++nt)
#pragma unroll
            for (int r = 0; r < 4; ++r)
                pb[(size_t)(rowbase + quad * 4 + r) * DDIM + nt * 16 + c] = acc[nt][r];
    }
}

// ---------------- kD4: merge 4 column-quarter partials, normalize, ELU, store.
__global__ __launch_bounds__(256) void kD_merge4(
        const float* __restrict__ pacc, const float* __restrict__ pl,
        float* __restrict__ out) {
    int i = blockIdx.x * 256 + threadIdx.x;          // floatx4 index, 262144 total
    const int Q = NN * DDIM / 4;
    const floatx4* p4 = (const floatx4*)pacc;
    floatx4 a0 = p4[i], a1 = p4[i + Q], a2 = p4[i + 2 * Q], a3 = p4[i + 3 * Q];
    int row = i >> 5;                                // 32 floatx4 per row
    float s = pl[row] + pl[NN + row] + pl[2 * NN + row] + pl[3 * NN + row];
    float inv = (s > 0.0f) ? 1.0f / s : 0.0f;
    floatx4 h;
#pragma unroll
    for (int r = 0; r < 4; ++r) {
        float v = (a0[r] + a1[r] + a2[r] + a3[r]) * inv;
        h[r] = (v > 0.0f) ? v : expm1f(v);
    }
    ((floatx4*)out)[i] = h;
}

// ---------------- kC2/kD2: the measured R6 2-way fallback (workspace-lean).
__global__ __launch_bounds__(256, 4) void kC_attn2(
        const int* __restrict__ adj,
        const unsigned short* __restrict__ WhB,
        const float* __restrict__ f, const float* __restrict__ g,
        float* __restrict__ pacc, float* __restrict__ pl) {
    __shared__ float smem[8192];
    int tid = threadIdx.x;
    int wave = tid >> 6, lane = tid & 63;
    int quad = lane >> 4, c = lane & 15;
    int bq   = blockIdx.x >> 9;
    int brow = blockIdx.x & 511;
    int rowbase = brow * 16;

    {
        const floatx4* g4 = (const floatx4*)g;
        for (int i = tid; i < 1024; i += 256)
            ((floatx4*)smem)[i] = g4[bq * 1024 + i];
    }
    __syncthreads();

    float f0 = f[rowbase + c];

    floatx4 acc[8];
#pragma unroll
    for (int nt = 0; nt < 8; ++nt) acc[nt] = (floatx4)(0.0f);
    float l0 = 0.0f;

    const intx4* arow = (const intx4*)(adj + (size_t)(rowbase + c) * NN);
    const short8* WhB8 = (const short8*)WhB;
    int jbase = bq * 128;

    intx4 A0a = arow[(jbase + 0 * 4 + wave) * 8 + quad * 2];
    intx4 A0b = arow[(jbase + 0 * 4 + wave) * 8 + quad * 2 + 1];
    intx4 A1a = arow[(jbase + 1 * 4 + wave) * 8 + quad * 2];
    intx4 A1b = arow[(jbase + 1 * 4 + wave) * 8 + quad * 2 + 1];

    short8 bfrA[8], bfrB[8];
#pragma unroll
    for (int nt = 0; nt < 8; ++nt)
        bfrA[nt] = WhB8[((size_t)(jbase + wave) * 8 + nt) * 64 + lane];

#define KC_STEP(ITC, BCUR, BNEXT) do {                                          \
        int j4n_ = jbase + (((ITC) + 2) & 31) * 4 + wave;                       \
        intx4 A2a_ = arow[j4n_ * 8 + quad * 2];                                 \
        intx4 A2b_ = arow[j4n_ * 8 + quad * 2 + 1];                             \
        int J32n_ = jbase + (((ITC) + 1) & 31) * 4 + wave;                      \
        _Pragma("unroll")                                                       \
        for (int nt = 0; nt < 8; ++nt)                                          \
            BNEXT[nt] = WhB8[((size_t)J32n_ * 8 + nt) * 64 + lane];             \
        int gb_ = ((ITC) * 4 + wave) * 32 + quad * 8;                           \
        floatx4 g0_ = *(const floatx4*)&smem[gb_];                              \
        floatx4 g1_ = *(const floatx4*)&smem[gb_ + 4];                          \
        short8 afr_;                                                            \
        _Pragma("unroll")                                                       \
        for (int u = 0; u < 4; ++u) {                                           \
            float x_, E_;                                                       \
            x_ = f0 + g0_[u]; x_ = fmaxf(x_, 0.2f * x_);                        \
            E_ = (A0a[u] > 0) ? __expf(x_) : 0.0f; l0 += E_;                    \
            afr_[u] = (short)f2bf(E_);                                          \
            x_ = f0 + g1_[u]; x_ = fmaxf(x_, 0.2f * x_);                        \
            E_ = (A0b[u] > 0) ? __expf(x_) : 0.0f; l0 += E_;                    \
            afr_[4 + u] = (short)f2bf(E_);                                      \
        }                                                                       \
        _Pragma("unroll")                                                       \
        for (int nt = 0; nt < 8; ++nt)                                          \
            acc[nt] = __builtin_amdgcn_mfma_f32_16x16x32_bf16(afr_, BCUR[nt],   \
                                                              acc[nt], 0, 0, 0);\
        A0a = A1a; A0b = A1b; A1a = A2a_; A1b = A2b_;                           \
    } while (0)

    for (int it = 0; it < 32; it += 2) {
        KC_STEP(it, bfrA, bfrB);
        KC_STEP(it + 1, bfrB, bfrA);
    }
#undef KC_STEP

    __syncthreads();
    smem[7000 + wave * 64 + lane] = l0;
    __syncthreads();
    if (tid < 16) {
        float s = 0.0f;
#pragma unroll
        for (int w = 0; w < 4; ++w)
#pragma unroll
            for (int q = 0; q < 4; ++q)
                s += smem[7000 + w * 64 + q * 16 + tid];
        pl[bq * NN + rowbase + tid] = s;
    }

    if (wave >= 2) {
        float* b = &smem[(wave - 2) * 2304 + lane * 36];
#pragma unroll
        for (int nt = 0; nt < 8; ++nt) *(floatx4*)&b[nt * 4] = acc[nt];
    }
    __syncthreads();
    if (wave < 2) {
        float* b = &smem[wave * 2304 + lane * 36];
#pragma unroll
        for (int nt = 0; nt < 8; ++nt) acc[nt] += *(const floatx4*)&b[nt * 4];
    }
    __syncthreads();
    if (wave == 1) {
        float* b = &smem[lane * 36];
#pragma unroll
        for (int nt = 0; nt < 8; ++nt) *(floatx4*)&b[nt * 4] = acc[nt];
    }
    __syncthreads();

    if (wave == 0) {
        float* b = &smem[lane * 36];
#pragma unroll
        for (int nt = 0; nt < 8; ++nt) acc[nt] += *(const floatx4*)&b[nt * 4];
        float* pb = pacc + (size_t)bq * NN * DDIM;
#pragma unroll
        for (int nt = 0; nt < 8; ++nt)
#pragma unroll
            for (int r = 0; r < 4; ++r)
                pb[(size_t)(rowbase + quad * 4 + r) * DDIM + nt * 16 + c] = acc[nt][r];
    }
}

__global__ __launch_bounds__(256) void kD_merge2(
        const float* __restrict__ pacc, const float* __restrict__ pl,
        float* __restrict__ out) {
    int i = blockIdx.x * 256 + threadIdx.x;
    const floatx4* p4 = (const floatx4*)pacc;
    floatx4 a = p4[i];
    floatx4 b = p4[i + NN * DDIM / 4];
    int row = i >> 5;
    float s = pl[row] + pl[NN + row];
    float inv = (s > 0.0f) ? 1.0f / s : 0.0f;
    floatx4 h;
#pragma unroll
    for (int r = 0; r < 4; ++r) {
        float v = (a[r] + b[r]) * inv;
        h[r] = (v > 0.0f) ? v : expm1f(v);
    }
    ((floatx4*)out)[i] = h;
}

extern "C" void kernel_launch(void* const* d_in, const int* in_sizes, int n_in,
                              void* d_out, int out_size, void* d_ws, size_t ws_size,
                              hipStream_t stream) {
    float* out = (float*)d_out;

    const void *p_adj = nullptr, *p_X = nullptr, *p_W = nullptr, *p_a = nullptr;
    for (int i = 0; i < n_in; ++i) {
        switch (in_sizes[i]) {
            case NN * NN:     p_adj = d_in[i]; break;
            case NN * KDIM:   p_X   = d_in[i]; break;
            case KDIM * DDIM: p_W   = d_in[i]; break;
            case 2 * DDIM:    p_a   = d_in[i]; break;
            default: break;
        }
    }
    if (!p_adj || !p_X || !p_W || !p_a) {
        k_trip<<<dim3(1), dim3(64), 0, stream>>>(out, 99999.0f);
        return;
    }

    size_t off_WB   = 0;                                   // 64 KB
    size_t off_WhB  = off_WB + 65536;                      // 2 MB
    size_t off_f    = off_WhB + (size_t)NN * DDIM * 2;     // 32 KB
    size_t off_g    = off_f + NN * 4;                      // 32 KB
    size_t off_pacc = off_g + NN * 4;                      // partials
    size_t needed4  = off_pacc + (size_t)4 * NN * DDIM * 4 + (size_t)4 * NN * 4;
    size_t needed2  = off_pacc + (size_t)2 * NN * DDIM * 4 + (size_t)2 * NN * 4;
    if (ws_size < needed2) {
        k_trip<<<dim3(1), dim3(64), 0, stream>>>(out, 12345.0f);
        return;
    }
    char* ws = (char*)d_ws;
    unsigned short* WB   = (unsigned short*)(ws + off_WB);
    unsigned short* WhB  = (unsigned short*)(ws + off_WhB);
    float*          f    = (float*)(ws + off_f);
    float*          g    = (float*)(ws + off_g);
    float*          pacc = (float*)(ws + off_pacc);

    const int*   adj = (const int*)p_adj;
    const float* X   = (const float*)p_X;
    const float* W   = (const float*)p_W;
    const float* a   = (const float*)p_a;

    kA_swizzleW<<<dim3(16), dim3(256), 0, stream>>>(W, WB);
    kB_wh<<<dim3(128), dim3(256), 0, stream>>>(X, WB, a, WhB, f, g);

    if (ws_size >= needed4) {
        float* pl = (float*)(ws + off_pacc + (size_t)4 * NN * DDIM * 4);
        kC_attn4<<<dim3(2048), dim3(256), 0, stream>>>(adj, WhB, f, g, pacc, pl);
        kD_merge4<<<dim3(NN * DDIM / 4 / 256), dim3(256), 0, stream>>>(pacc, pl, out);
    } else {
        float* pl = (float*)(ws + off_pacc + (size_t)2 * NN * DDIM * 4);
        kC_attn2<<<dim3(1024), dim3(256), 0, stream>>>(adj, WhB, f, g, pacc, pl);
        kD_merge2<<<dim3(NN * DDIM / 4 / 256), dim3(256), 0, stream>>>(pacc, pl, out);
    }
}

// Round 9
// 448.772 us; speedup vs baseline: 1.5050x; 1.5050x over previous
//
#include <hip/hip_runtime.h>
#include <hip/hip_bf16.h>

#define NN 8192
#define KDIM 256
#define DDIM 128

typedef __attribute__((ext_vector_type(8))) short short8;
typedef __attribute__((ext_vector_type(4))) float floatx4;
typedef __attribute__((ext_vector_type(4))) int intx4;

__device__ __forceinline__ unsigned short f2bf(float x) {
    unsigned int u = __float_as_uint(x);
    return (unsigned short)((u + 0x8000u) >> 16);
}

__global__ void k_trip(float* out, float v) {
    if (threadIdx.x == 0 && blockIdx.x == 0) out[0] = v;
}

// ---------------- kA: swizzle W (256x128 fp32 row-major) into bf16 B-fragment layout
__global__ void kA_swizzleW(const float* __restrict__ W, unsigned short* __restrict__ WB) {
    int gid = blockIdx.x * blockDim.x + threadIdx.x;   // 0..4095
    int kt = gid >> 9, nt = (gid >> 6) & 7, lane = gid & 63;
    int quad = lane >> 4, c = lane & 15;
    short8 pack;
#pragma unroll
    for (int t = 0; t < 8; ++t)
        pack[t] = (short)f2bf(W[(kt * 32 + quad * 8 + t) * DDIM + nt * 16 + c]);
    *(short8*)(WB + ((size_t)(kt * 8 + nt) * 64 + lane) * 8) = pack;
}

// ---------------- kB: Wh = X @ W (bf16 MFMA); emit f, g, and WhB fragments.
__global__ __launch_bounds__(256) void kB_wh(
        const float* __restrict__ X,
        const unsigned short* __restrict__ WB,
        const float* __restrict__ a,
        unsigned short* __restrict__ WhB,
        float* __restrict__ f, float* __restrict__ g) {
    __shared__ unsigned short tile[64 * 128];
    int tid = threadIdx.x;
    int wave = tid >> 6, lane = tid & 63;
    int quad = lane >> 4, c = lane & 15;
    int rowbase = blockIdx.x * 64 + wave * 16;

    floatx4 acc[8];
#pragma unroll
    for (int nt = 0; nt < 8; ++nt) acc[nt] = (floatx4)(0.0f);

    const short8* WB8 = (const short8*)WB;
#pragma unroll
    for (int ks = 0; ks < 8; ++ks) {
        const float* xp = X + (size_t)(rowbase + c) * KDIM + ks * 32 + quad * 8;
        floatx4 x0 = *(const floatx4*)xp;
        floatx4 x1 = *(const floatx4*)(xp + 4);
        short8 afrag;
#pragma unroll
        for (int t = 0; t < 4; ++t) { afrag[t] = (short)f2bf(x0[t]); afrag[4 + t] = (short)f2bf(x1[t]); }
#pragma unroll
        for (int nt = 0; nt < 8; ++nt) {
            short8 b = WB8[(ks * 8 + nt) * 64 + lane];
            acc[nt] = __builtin_amdgcn_mfma_f32_16x16x32_bf16(afrag, b, acc[nt], 0, 0, 0);
        }
    }

    float fp[4] = {0.f, 0.f, 0.f, 0.f}, gp[4] = {0.f, 0.f, 0.f, 0.f};
#pragma unroll
    for (int nt = 0; nt < 8; ++nt) {
        float a1 = a[nt * 16 + c];
        float a2 = a[DDIM + nt * 16 + c];
#pragma unroll
        for (int r = 0; r < 4; ++r) {
            fp[r] += acc[nt][r] * a1;
            gp[r] += acc[nt][r] * a2;
        }
    }
#pragma unroll
    for (int m = 1; m < 16; m <<= 1) {
#pragma unroll
        for (int r = 0; r < 4; ++r) {
            fp[r] += __shfl_xor(fp[r], m);
            gp[r] += __shfl_xor(gp[r], m);
        }
    }
    if (c == 0) {
#pragma unroll
        for (int r = 0; r < 4; ++r) {
            f[rowbase + quad * 4 + r] = fp[r];
            g[rowbase + quad * 4 + r] = gp[r];
        }
    }

#pragma unroll
    for (int nt = 0; nt < 8; ++nt)
#pragma unroll
        for (int r = 0; r < 4; ++r)
            tile[(wave * 16 + quad * 4 + r) * 128 + nt * 16 + c] = f2bf(acc[nt][r]);
    __syncthreads();

    int kt2 = wave >> 1;
#pragma unroll
    for (int ntj = 0; ntj < 4; ++ntj) {
        int nt = (wave & 1) * 4 + ntj;
        short8 pack;
#pragma unroll
        for (int t = 0; t < 8; ++t)
            pack[t] = (short)tile[(kt2 * 32 + quad * 8 + t) * 128 + nt * 16 + c];
        *(short8*)(WhB + ((size_t)((blockIdx.x * 2 + kt2) * 8 + nt) * 64 + lane) * 8) = pack;
    }
}

// ---------------- kC4: masked-softmax attention, 4-way column split, LEAN REGISTERS.
// R8 post-mortem: __launch_bounds__(256,8) forced a 64-VGPR-class budget on a
// ~115-reg kernel -> scratch spills (WRITE_SIZE 653 MB, kC 397 us). The VGPR wall
// makes 8 blocks/CU unreachable with acc[8]=32 regs + 64-reg double-buffer.
// This version: NO WhB double-buffer (-32 regs), adjacency prefetch 1-deep (-8),
// __launch_bounds__(256,5) = 102-reg budget, ~90 needed -> no spill, 5 blocks/CU.
// TLP (20 waves/CU) replaces ILP as the latency-hiding mechanism.
__global__ __launch_bounds__(256, 5) void kC_attn4(
        const int* __restrict__ adj,
        const unsigned short* __restrict__ WhB,
        const float* __restrict__ f, const float* __restrict__ g,
        float* __restrict__ pacc, float* __restrict__ pl) {
    __shared__ float smem[4880];    // 19.5 KB: [0,2048) g-slice, then merge overlay
    int tid = threadIdx.x;
    int wave = tid >> 6, lane = tid & 63;
    int quad = lane >> 4, c = lane & 15;
    int bq   = blockIdx.x >> 9;          // column quarter 0..3
    int brow = blockIdx.x & 511;         // 16-row group
    int rowbase = brow * 16;

    // stage this quarter's g-slice: 2048 floats
    {
        const floatx4* g4 = (const floatx4*)g;
        for (int i = tid; i < 512; i += 256)
            ((floatx4*)smem)[i] = g4[bq * 512 + i];
    }
    __syncthreads();

    float f0 = f[rowbase + c];

    floatx4 acc[8];
#pragma unroll
    for (int nt = 0; nt < 8; ++nt) acc[nt] = (floatx4)(0.0f);
    float l0 = 0.0f;

    const intx4* arow = (const intx4*)(adj + (size_t)(rowbase + c) * NN);
    const short8* WhB8 = (const short8*)WhB;
    int jbase = bq * 64;                 // J32 range [jbase, jbase+64)

    // adjacency prefetch 1-deep: it=0
    intx4 A0a = arow[(jbase + wave) * 8 + quad * 2];
    intx4 A0b = arow[(jbase + wave) * 8 + quad * 2 + 1];

#pragma unroll 2
    for (int it = 0; it < 16; ++it) {
        // prefetch adjacency it+1 (wrap harmlessly at tail)
        int j4n = jbase + ((it + 1) & 15) * 4 + wave;
        intx4 A1a = arow[j4n * 8 + quad * 2];
        intx4 A1b = arow[j4n * 8 + quad * 2 + 1];

        // WhB fragments for THIS step (no dbuf; L2-latency hidden by TLP + exp VALU)
        int J32 = jbase + it * 4 + wave;
        short8 bfr[8];
#pragma unroll
        for (int nt = 0; nt < 8; ++nt)
            bfr[nt] = WhB8[((size_t)J32 * 8 + nt) * 64 + lane];

        int gb = (it * 4 + wave) * 32 + quad * 8;
        floatx4 g0 = *(const floatx4*)&smem[gb];
        floatx4 g1 = *(const floatx4*)&smem[gb + 4];

        short8 afr;
#pragma unroll
        for (int u = 0; u < 4; ++u) {
            float x, E;
            x = f0 + g0[u]; x = fmaxf(x, 0.2f * x);
            E = (A0a[u] > 0) ? __expf(x) : 0.0f; l0 += E; afr[u] = (short)f2bf(E);
            x = f0 + g1[u]; x = fmaxf(x, 0.2f * x);
            E = (A0b[u] > 0) ? __expf(x) : 0.0f; l0 += E; afr[4 + u] = (short)f2bf(E);
        }

#pragma unroll
        for (int nt = 0; nt < 8; ++nt)
            acc[nt] = __builtin_amdgcn_mfma_f32_16x16x32_bf16(afr, bfr[nt], acc[nt], 0, 0, 0);

        A0a = A1a; A0b = A1b;
    }

    // ---- l partial ----
    __syncthreads();                      // g reads done; smem reusable
    smem[4608 + wave * 64 + lane] = l0;
    __syncthreads();
    if (tid < 16) {
        float s = 0.0f;
#pragma unroll
        for (int w = 0; w < 4; ++w)
#pragma unroll
            for (int q = 0; q < 4; ++q)
                s += smem[4608 + w * 64 + q * 16 + tid];
        pl[bq * NN + rowbase + tid] = s;
    }

    // ---- acc merge across 4 waves (stride-36 padded buffers at smem[0..4607]) ----
    if (wave >= 2) {
        float* b = &smem[(wave - 2) * 2304 + lane * 36];
#pragma unroll
        for (int nt = 0; nt < 8; ++nt) *(floatx4*)&b[nt * 4] = acc[nt];
    }
    __syncthreads();
    if (wave < 2) {
        float* b = &smem[wave * 2304 + lane * 36];
#pragma unroll
        for (int nt = 0; nt < 8; ++nt) acc[nt] += *(const floatx4*)&b[nt * 4];
    }
    __syncthreads();
    if (wave == 1) {
        float* b = &smem[lane * 36];
#pragma unroll
        for (int nt = 0; nt < 8; ++nt) *(floatx4*)&b[nt * 4] = acc[nt];
    }
    __syncthreads();

    // ---- write partial acc (wave 0), unnormalized ----
    if (wave == 0) {
        float* b = &smem[lane * 36];
#pragma unroll
        for (int nt = 0; nt < 8; ++nt) acc[nt] += *(const floatx4*)&b[nt * 4];
        float* pb = pacc + (size_t)bq * NN * DDIM;
#pragma unroll
        for (int nt = 0; nt < 8; ++nt)
#pragma unroll
            for (int r = 0; r < 4; ++r)
                pb[(size_t)(rowbase + quad * 4 + r) * DDIM + nt * 16 + c] = acc[nt][r];
    }
}

// ---------------- kD4: merge 4 column-quarter partials, normalize, ELU, store.
__global__ __launch_bounds__(256) void kD_merge4(
        const float* __restrict__ pacc, const float* __restrict__ pl,
        float* __restrict__ out) {
    int i = blockIdx.x * 256 + threadIdx.x;          // floatx4 index, 262144 total
    const int Q = NN * DDIM / 4;
    const floatx4* p4 = (const floatx4*)pacc;
    floatx4 a0 = p4[i], a1 = p4[i + Q], a2 = p4[i + 2 * Q], a3 = p4[i + 3 * Q];
    int row = i >> 5;                                // 32 floatx4 per row
    float s = pl[row] + pl[NN + row] + pl[2 * NN + row] + pl[3 * NN + row];
    float inv = (s > 0.0f) ? 1.0f / s : 0.0f;
    floatx4 h;
#pragma unroll
    for (int r = 0; r < 4; ++r) {
        float v = (a0[r] + a1[r] + a2[r] + a3[r]) * inv;
        h[r] = (v > 0.0f) ? v : expm1f(v);
    }
    ((floatx4*)out)[i] = h;
}

// ---------------- kC2/kD2: the measured R6 2-way fallback (workspace-lean).
__global__ __launch_bounds__(256, 4) void kC_attn2(
        const int* __restrict__ adj,
        const unsigned short* __restrict__ WhB,
        const float* __restrict__ f, const float* __restrict__ g,
        float* __restrict__ pacc, float* __restrict__ pl) {
    __shared__ float smem[8192];
    int tid = threadIdx.x;
    int wave = tid >> 6, lane = tid & 63;
    int quad = lane >> 4, c = lane & 15;
    int bq   = blockIdx.x >> 9;
    int brow = blockIdx.x & 511;
    int rowbase = brow * 16;

    {
        const floatx4* g4 = (const floatx4*)g;
        for (int i = tid; i < 1024; i += 256)
            ((floatx4*)smem)[i] = g4[bq * 1024 + i];
    }
    __syncthreads();

    float f0 = f[rowbase + c];

    floatx4 acc[8];
#pragma unroll
    for (int nt = 0; nt < 8; ++nt) acc[nt] = (floatx4)(0.0f);
    float l0 = 0.0f;

    const intx4* arow = (const intx4*)(adj + (size_t)(rowbase + c) * NN);
    const short8* WhB8 = (const short8*)WhB;
    int jbase = bq * 128;

    intx4 A0a = arow[(jbase + 0 * 4 + wave) * 8 + quad * 2];
    intx4 A0b = arow[(jbase + 0 * 4 + wave) * 8 + quad * 2 + 1];
    intx4 A1a = arow[(jbase + 1 * 4 + wave) * 8 + quad * 2];
    intx4 A1b = arow[(jbase + 1 * 4 + wave) * 8 + quad * 2 + 1];

    short8 bfrA[8], bfrB[8];
#pragma unroll
    for (int nt = 0; nt < 8; ++nt)
        bfrA[nt] = WhB8[((size_t)(jbase + wave) * 8 + nt) * 64 + lane];

#define KC_STEP(ITC, BCUR, BNEXT) do {                                          \
        int j4n_ = jbase + (((ITC) + 2) & 31) * 4 + wave;                       \
        intx4 A2a_ = arow[j4n_ * 8 + quad * 2];                                 \
        intx4 A2b_ = arow[j4n_ * 8 + quad * 2 + 1];                             \
        int J32n_ = jbase + (((ITC) + 1) & 31) * 4 + wave;                      \
        _Pragma("unroll")                                                       \
        for (int nt = 0; nt < 8; ++nt)                                          \
            BNEXT[nt] = WhB8[((size_t)J32n_ * 8 + nt) * 64 + lane];             \
        int gb_ = ((ITC) * 4 + wave) * 32 + quad * 8;                           \
        floatx4 g0_ = *(const floatx4*)&smem[gb_];                              \
        floatx4 g1_ = *(const floatx4*)&smem[gb_ + 4];                          \
        short8 afr_;                                                            \
        _Pragma("unroll")                                                       \
        for (int u = 0; u < 4; ++u) {                                           \
            float x_, E_;                                                       \
            x_ = f0 + g0_[u]; x_ = fmaxf(x_, 0.2f * x_);                        \
            E_ = (A0a[u] > 0) ? __expf(x_) : 0.0f; l0 += E_;                    \
            afr_[u] = (short)f2bf(E_);                                          \
            x_ = f0 + g1_[u]; x_ = fmaxf(x_, 0.2f * x_);                        \
            E_ = (A0b[u] > 0) ? __expf(x_) : 0.0f; l0 += E_;                    \
            afr_[4 + u] = (short)f2bf(E_);                                      \
        }                                                                       \
        _Pragma("unroll")                                                       \
        for (int nt = 0; nt < 8; ++nt)                                          \
            acc[nt] = __builtin_amdgcn_mfma_f32_16x16x32_bf16(afr_, BCUR[nt],   \
                                                              acc[nt], 0, 0, 0);\
        A0a = A1a; A0b = A1b; A1a = A2a_; A1b = A2b_;                           \
    } while (0)

    for (int it = 0; it < 32; it += 2) {
        KC_STEP(it, bfrA, bfrB);
        KC_STEP(it + 1, bfrB, bfrA);
    }
#undef KC_STEP

    __syncthreads();
    smem[7000 + wave * 64 + lane] = l0;
    __syncthreads();
    if (tid < 16) {
        float s = 0.0f;
#pragma unroll
        for (int w = 0; w < 4; ++w)
#pragma unroll
            for (int q = 0; q < 4; ++q)
                s += smem[7000 + w * 64 + q * 16 + tid];
        pl[bq * NN + rowbase + tid] = s;
    }

    if (wave >= 2) {
        float* b = &smem[(wave - 2) * 2304 + lane * 36];
#pragma unroll
        for (int nt = 0; nt < 8; ++nt) *(floatx4*)&b[nt * 4] = acc[nt];
    }
    __syncthreads();
    if (wave < 2) {
        float* b = &smem[wave * 2304 + lane * 36];
#pragma unroll
        for (int nt = 0; nt < 8; ++nt) acc[nt] += *(const floatx4*)&b[nt * 4];
    }
    __syncthreads();
    if (wave == 1) {
        float* b = &smem[lane * 36];
#pragma unroll
        for (int nt = 0; nt < 8; ++nt) *(floatx4*)&b[nt * 4] = acc[nt];
    }
    __syncthreads();

    if (wave == 0) {
        float* b = &smem[lane * 36];
#pragma unroll
        for (int nt = 0; nt < 8; ++nt) acc[nt] += *(const floatx4*)&b[nt * 4];
        float* pb = pacc + (size_t)bq * NN * DDIM;
#pragma unroll
        for (int nt = 0; nt < 8; ++nt)
#pragma unroll
            for (int r = 0; r < 4; ++r)
                pb[(size_t)(rowbase + quad * 4 + r) * DDIM + nt * 16 + c] = acc[nt][r];
    }
}

__global__ __launch_bounds__(256) void kD_merge2(
        const float* __restrict__ pacc, const float* __restrict__ pl,
        float* __restrict__ out) {
    int i = blockIdx.x * 256 + threadIdx.x;
    const floatx4* p4 = (const floatx4*)pacc;
    floatx4 a = p4[i];
    floatx4 b = p4[i + NN * DDIM / 4];
    int row = i >> 5;
    float s = pl[row] + pl[NN + row];
    float inv = (s > 0.0f) ? 1.0f / s : 0.0f;
    floatx4 h;
#pragma unroll
    for (int r = 0; r < 4; ++r) {
        float v = (a[r] + b[r]) * inv;
        h[r] = (v > 0.0f) ? v : expm1f(v);
    }
    ((floatx4*)out)[i] = h;
}

extern "C" void kernel_launch(void* const* d_in, const int* in_sizes, int n_in,
                              void* d_out, int out_size, void* d_ws, size_t ws_size,
                              hipStream_t stream) {
    float* out = (float*)d_out;

    const void *p_adj = nullptr, *p_X = nullptr, *p_W = nullptr, *p_a = nullptr;
    for (int i = 0; i < n_in; ++i) {
        switch (in_sizes[i]) {
            case NN * NN:     p_adj = d_in[i]; break;
            case NN * KDIM:   p_X   = d_in[i]; break;
            case KDIM * DDIM: p_W   = d_in[i]; break;
            case 2 * DDIM:    p_a   = d_in[i]; break;
            default: break;
        }
    }
    if (!p_adj || !p_X || !p_W || !p_a) {
        k_trip<<<dim3(1), dim3(64), 0, stream>>>(out, 99999.0f);
        return;
    }

    size_t off_WB   = 0;                                   // 64 KB
    size_t off_WhB  = off_WB + 65536;                      // 2 MB
    size_t off_f    = off_WhB + (size_t)NN * DDIM * 2;     // 32 KB
    size_t off_g    = off_f + NN * 4;                      // 32 KB
    size_t off_pacc = off_g + NN * 4;                      // partials
    size_t needed4  = off_pacc + (size_t)4 * NN * DDIM * 4 + (size_t)4 * NN * 4;
    size_t needed2  = off_pacc + (size_t)2 * NN * DDIM * 4 + (size_t)2 * NN * 4;
    if (ws_size < needed2) {
        k_trip<<<dim3(1), dim3(64), 0, stream>>>(out, 12345.0f);
        return;
    }
    char* ws = (char*)d_ws;
    unsigned short* WB   = (unsigned short*)(ws + off_WB);
    unsigned short* WhB  = (unsigned short*)(ws + off_WhB);
    float*          f    = (float*)(ws + off_f);
    float*          g    = (float*)(ws + off_g);
    float*          pacc = (float*)(ws + off_pacc);

    const int*   adj = (const int*)p_adj;
    const float* X   = (const float*)p_X;
    const float* W   = (const float*)p_W;
    const float* a   = (const float*)p_a;

    kA_swizzleW<<<dim3(16), dim3(256), 0, stream>>>(W, WB);
    kB_wh<<<dim3(128), dim3(256), 0, stream>>>(X, WB, a, WhB, f, g);

    if (ws_size >= needed4) {
        float* pl = (float*)(ws + off_pacc + (size_t)4 * NN * DDIM * 4);
        kC_attn4<<<dim3(2048), dim3(256), 0, stream>>>(adj, WhB, f, g, pacc, pl);
        kD_merge4<<<dim3(NN * DDIM / 4 / 256), dim3(256), 0, stream>>>(pacc, pl, out);
    } else {
        float* pl = (float*)(ws + off_pacc + (size_t)2 * NN * DDIM * 4);
        kC_attn2<<<dim3(1024), dim3(256), 0, stream>>>(adj, WhB, f, g, pacc, pl);
        kD_merge2<<<dim3(NN * DDIM / 4 / 256), dim3(256), 0, stream>>>(pacc, pl, out);
    }
}

// Round 10
// 432.807 us; speedup vs baseline: 1.5605x; 1.0369x over previous
//
#include <hip/hip_runtime.h>
#include <hip/hip_bf16.h>

#define NN 8192
#define KDIM 256
#define DDIM 128

typedef __attribute__((ext_vector_type(8))) short short8;
typedef __attribute__((ext_vector_type(4))) float floatx4;
typedef __attribute__((ext_vector_type(4))) int intx4;

__device__ __forceinline__ unsigned short f2bf(float x) {
    unsigned int u = __float_as_uint(x);
    return (unsigned short)((u + 0x8000u) >> 16);
}

__global__ void k_trip(float* out, float v) {
    if (threadIdx.x == 0 && blockIdx.x == 0) out[0] = v;
}

// ---------------- kA: swizzle W (256x128 fp32 row-major) into bf16 B-fragment layout
__global__ void kA_swizzleW(const float* __restrict__ W, unsigned short* __restrict__ WB) {
    int gid = blockIdx.x * blockDim.x + threadIdx.x;   // 0..4095
    int kt = gid >> 9, nt = (gid >> 6) & 7, lane = gid & 63;
    int quad = lane >> 4, c = lane & 15;
    short8 pack;
#pragma unroll
    for (int t = 0; t < 8; ++t)
        pack[t] = (short)f2bf(W[(kt * 32 + quad * 8 + t) * DDIM + nt * 16 + c]);
    *(short8*)(WB + ((size_t)(kt * 8 + nt) * 64 + lane) * 8) = pack;
}

// ---------------- kB: Wh = X @ W (bf16 MFMA); emit f, g, and WhB fragments.
__global__ __launch_bounds__(256) void kB_wh(
        const float* __restrict__ X,
        const unsigned short* __restrict__ WB,
        const float* __restrict__ a,
        unsigned short* __restrict__ WhB,
        float* __restrict__ f, float* __restrict__ g) {
    __shared__ unsigned short tile[64 * 128];
    int tid = threadIdx.x;
    int wave = tid >> 6, lane = tid & 63;
    int quad = lane >> 4, c = lane & 15;
    int rowbase = blockIdx.x * 64 + wave * 16;

    floatx4 acc[8];
#pragma unroll
    for (int nt = 0; nt < 8; ++nt) acc[nt] = (floatx4)(0.0f);

    const short8* WB8 = (const short8*)WB;
#pragma unroll
    for (int ks = 0; ks < 8; ++ks) {
        const float* xp = X + (size_t)(rowbase + c) * KDIM + ks * 32 + quad * 8;
        floatx4 x0 = *(const floatx4*)xp;
        floatx4 x1 = *(const floatx4*)(xp + 4);
        short8 afrag;
#pragma unroll
        for (int t = 0; t < 4; ++t) { afrag[t] = (short)f2bf(x0[t]); afrag[4 + t] = (short)f2bf(x1[t]); }
#pragma unroll
        for (int nt = 0; nt < 8; ++nt) {
            short8 b = WB8[(ks * 8 + nt) * 64 + lane];
            acc[nt] = __builtin_amdgcn_mfma_f32_16x16x32_bf16(afrag, b, acc[nt], 0, 0, 0);
        }
    }

    float fp[4] = {0.f, 0.f, 0.f, 0.f}, gp[4] = {0.f, 0.f, 0.f, 0.f};
#pragma unroll
    for (int nt = 0; nt < 8; ++nt) {
        float a1 = a[nt * 16 + c];
        float a2 = a[DDIM + nt * 16 + c];
#pragma unroll
        for (int r = 0; r < 4; ++r) {
            fp[r] += acc[nt][r] * a1;
            gp[r] += acc[nt][r] * a2;
        }
    }
#pragma unroll
    for (int m = 1; m < 16; m <<= 1) {
#pragma unroll
        for (int r = 0; r < 4; ++r) {
            fp[r] += __shfl_xor(fp[r], m);
            gp[r] += __shfl_xor(gp[r], m);
        }
    }
    if (c == 0) {
#pragma unroll
        for (int r = 0; r < 4; ++r) {
            f[rowbase + quad * 4 + r] = fp[r];
            g[rowbase + quad * 4 + r] = gp[r];
        }
    }

#pragma unroll
    for (int nt = 0; nt < 8; ++nt)
#pragma unroll
        for (int r = 0; r < 4; ++r)
            tile[(wave * 16 + quad * 4 + r) * 128 + nt * 16 + c] = f2bf(acc[nt][r]);
    __syncthreads();

    int kt2 = wave >> 1;
#pragma unroll
    for (int ntj = 0; ntj < 4; ++ntj) {
        int nt = (wave & 1) * 4 + ntj;
        short8 pack;
#pragma unroll
        for (int t = 0; t < 8; ++t)
            pack[t] = (short)tile[(kt2 * 32 + quad * 8 + t) * 128 + nt * 16 + c];
        *(short8*)(WhB + ((size_t)((blockIdx.x * 2 + kt2) * 8 + nt) * 64 + lane) * 8) = pack;
    }
}

// ---------------- kC2: fused masked-softmax attention, 2-way column split.
// EXPERIMENT MATRIX (measured): R4 512b/dbuf/occ22 = 169us; R6 1024b/dbuf/occ50
// = ~118us (best); R9 2048b/NO-dbuf/occ44 = 171us; R8 2048b/spill = 397us.
// Occupancy without the register pipeline is worthless (R9); the pipeline's
// register cost (acc 32 + bfr dbuf 64 + misc ~ 130-144 unified regs) caps at
// 4 waves/SIMD -> R6's 4 blocks/CU is the practical occupancy max.
// THIS ROUND'S ONE CHANGE: inside KC_STEP, issue the WhB BNEXT loads BEFORE the
// adjacency prefetch. vmcnt retires strictly in issue order, so next step's MFMA
// (waiting on BNEXT) otherwise queues behind a fresh ~900cy HBM adjacency load.
// With BNEXT first, the wait drains at L2/L3 latency; adjacency is consumed 2
// steps later, fully covered by step wall time.
__global__ __launch_bounds__(256, 4) void kC_attn2(
        const int* __restrict__ adj,
        const unsigned short* __restrict__ WhB,
        const float* __restrict__ f, const float* __restrict__ g,
        float* __restrict__ pacc, float* __restrict__ pl) {
    __shared__ float smem[8192];
    int tid = threadIdx.x;
    int wave = tid >> 6, lane = tid & 63;
    int quad = lane >> 4, c = lane & 15;
    int bq   = blockIdx.x >> 9;
    int brow = blockIdx.x & 511;
    int rowbase = brow * 16;

    {
        const floatx4* g4 = (const floatx4*)g;
        for (int i = tid; i < 1024; i += 256)
            ((floatx4*)smem)[i] = g4[bq * 1024 + i];
    }
    __syncthreads();

    float f0 = f[rowbase + c];

    floatx4 acc[8];
#pragma unroll
    for (int nt = 0; nt < 8; ++nt) acc[nt] = (floatx4)(0.0f);
    float l0 = 0.0f;

    const intx4* arow = (const intx4*)(adj + (size_t)(rowbase + c) * NN);
    const short8* WhB8 = (const short8*)WhB;
    int jbase = bq * 128;

    intx4 A0a = arow[(jbase + 0 * 4 + wave) * 8 + quad * 2];
    intx4 A0b = arow[(jbase + 0 * 4 + wave) * 8 + quad * 2 + 1];
    intx4 A1a = arow[(jbase + 1 * 4 + wave) * 8 + quad * 2];
    intx4 A1b = arow[(jbase + 1 * 4 + wave) * 8 + quad * 2 + 1];

    short8 bfrA[8], bfrB[8];
#pragma unroll
    for (int nt = 0; nt < 8; ++nt)
        bfrA[nt] = WhB8[((size_t)(jbase + wave) * 8 + nt) * 64 + lane];

    // KC_STEP: WhB BNEXT loads issued FIRST, adjacency prefetch LAST (see header).
#define KC_STEP(ITC, BCUR, BNEXT) do {                                          \
        int J32n_ = jbase + (((ITC) + 1) & 31) * 4 + wave;                      \
        _Pragma("unroll")                                                       \
        for (int nt = 0; nt < 8; ++nt)                                          \
            BNEXT[nt] = WhB8[((size_t)J32n_ * 8 + nt) * 64 + lane];             \
        int j4n_ = jbase + (((ITC) + 2) & 31) * 4 + wave;                       \
        intx4 A2a_ = arow[j4n_ * 8 + quad * 2];                                 \
        intx4 A2b_ = arow[j4n_ * 8 + quad * 2 + 1];                             \
        int gb_ = ((ITC) * 4 + wave) * 32 + quad * 8;                           \
        floatx4 g0_ = *(const floatx4*)&smem[gb_];                              \
        floatx4 g1_ = *(const floatx4*)&smem[gb_ + 4];                          \
        short8 afr_;                                                            \
        _Pragma("unroll")                                                       \
        for (int u = 0; u < 4; ++u) {                                           \
            float x_, E_;                                                       \
            x_ = f0 + g0_[u]; x_ = fmaxf(x_, 0.2f * x_);                        \
            E_ = (A0a[u] > 0) ? __expf(x_) : 0.0f; l0 += E_;                    \
            afr_[u] = (short)f2bf(E_);                                          \
            x_ = f0 + g1_[u]; x_ = fmaxf(x_, 0.2f * x_);                        \
            E_ = (A0b[u] > 0) ? __expf(x_) : 0.0f; l0 += E_;                    \
            afr_[4 + u] = (short)f2bf(E_);                                      \
        }                                                                       \
        _Pragma("unroll")                                                       \
        for (int nt = 0; nt < 8; ++nt)                                          \
            acc[nt] = __builtin_amdgcn_mfma_f32_16x16x32_bf16(afr_, BCUR[nt],   \
                                                              acc[nt], 0, 0, 0);\
        A0a = A1a; A0b = A1b; A1a = A2a_; A1b = A2b_;                           \
    } while (0)

    for (int it = 0; it < 32; it += 2) {
        KC_STEP(it, bfrA, bfrB);
        KC_STEP(it + 1, bfrB, bfrA);
    }
#undef KC_STEP

    __syncthreads();
    smem[7000 + wave * 64 + lane] = l0;
    __syncthreads();
    if (tid < 16) {
        float s = 0.0f;
#pragma unroll
        for (int w = 0; w < 4; ++w)
#pragma unroll
            for (int q = 0; q < 4; ++q)
                s += smem[7000 + w * 64 + q * 16 + tid];
        pl[bq * NN + rowbase + tid] = s;
    }

    if (wave >= 2) {
        float* b = &smem[(wave - 2) * 2304 + lane * 36];
#pragma unroll
        for (int nt = 0; nt < 8; ++nt) *(floatx4*)&b[nt * 4] = acc[nt];
    }
    __syncthreads();
    if (wave < 2) {
        float* b = &smem[wave * 2304 + lane * 36];
#pragma unroll
        for (int nt = 0; nt < 8; ++nt) acc[nt] += *(const floatx4*)&b[nt * 4];
    }
    __syncthreads();
    if (wave == 1) {
        float* b = &smem[lane * 36];
#pragma unroll
        for (int nt = 0; nt < 8; ++nt) *(floatx4*)&b[nt * 4] = acc[nt];
    }
    __syncthreads();

    if (wave == 0) {
        float* b = &smem[lane * 36];
#pragma unroll
        for (int nt = 0; nt < 8; ++nt) acc[nt] += *(const floatx4*)&b[nt * 4];
        float* pb = pacc + (size_t)bq * NN * DDIM;
#pragma unroll
        for (int nt = 0; nt < 8; ++nt)
#pragma unroll
            for (int r = 0; r < 4; ++r)
                pb[(size_t)(rowbase + quad * 4 + r) * DDIM + nt * 16 + c] = acc[nt][r];
    }
}

__global__ __launch_bounds__(256) void kD_merge2(
        const float* __restrict__ pacc, const float* __restrict__ pl,
        float* __restrict__ out) {
    int i = blockIdx.x * 256 + threadIdx.x;
    const floatx4* p4 = (const floatx4*)pacc;
    floatx4 a = p4[i];
    floatx4 b = p4[i + NN * DDIM / 4];
    int row = i >> 5;
    float s = pl[row] + pl[NN + row];
    float inv = (s > 0.0f) ? 1.0f / s : 0.0f;
    floatx4 h;
#pragma unroll
    for (int r = 0; r < 4; ++r) {
        float v = (a[r] + b[r]) * inv;
        h[r] = (v > 0.0f) ? v : expm1f(v);
    }
    ((floatx4*)out)[i] = h;
}

extern "C" void kernel_launch(void* const* d_in, const int* in_sizes, int n_in,
                              void* d_out, int out_size, void* d_ws, size_t ws_size,
                              hipStream_t stream) {
    float* out = (float*)d_out;

    const void *p_adj = nullptr, *p_X = nullptr, *p_W = nullptr, *p_a = nullptr;
    for (int i = 0; i < n_in; ++i) {
        switch (in_sizes[i]) {
            case NN * NN:     p_adj = d_in[i]; break;
            case NN * KDIM:   p_X   = d_in[i]; break;
            case KDIM * DDIM: p_W   = d_in[i]; break;
            case 2 * DDIM:    p_a   = d_in[i]; break;
            default: break;
        }
    }
    if (!p_adj || !p_X || !p_W || !p_a) {
        k_trip<<<dim3(1), dim3(64), 0, stream>>>(out, 99999.0f);
        return;
    }

    size_t off_WB   = 0;                                   // 64 KB
    size_t off_WhB  = off_WB + 65536;                      // 2 MB
    size_t off_f    = off_WhB + (size_t)NN * DDIM * 2;     // 32 KB
    size_t off_g    = off_f + NN * 4;                      // 32 KB
    size_t off_pacc = off_g + NN * 4;                      // 2 x 4 MB partial acc
    size_t off_pl   = off_pacc + (size_t)2 * NN * DDIM * 4;// 2 x 32 KB partial l
    size_t needed   = off_pl + (size_t)2 * NN * 4;
    if (ws_size < needed) {
        k_trip<<<dim3(1), dim3(64), 0, stream>>>(out, 12345.0f);
        return;
    }
    char* ws = (char*)d_ws;
    unsigned short* WB   = (unsigned short*)(ws + off_WB);
    unsigned short* WhB  = (unsigned short*)(ws + off_WhB);
    float*          f    = (float*)(ws + off_f);
    float*          g    = (float*)(ws + off_g);
    float*          pacc = (float*)(ws + off_pacc);
    float*          pl   = (float*)(ws + off_pl);

    const int*   adj = (const int*)p_adj;
    const float* X   = (const float*)p_X;
    const float* W   = (const float*)p_W;
    const float* a   = (const float*)p_a;

    kA_swizzleW<<<dim3(16), dim3(256), 0, stream>>>(W, WB);
    kB_wh<<<dim3(128), dim3(256), 0, stream>>>(X, WB, a, WhB, f, g);
    kC_attn2<<<dim3(1024), dim3(256), 0, stream>>>(adj, WhB, f, g, pacc, pl);
    kD_merge2<<<dim3(NN * DDIM / 4 / 256), dim3(256), 0, stream>>>(pacc, pl, out);
}